// Round 1
// baseline (707.482 us; speedup 1.0000x reference)
//
#include <hip/hip_runtime.h>
#include <math.h>

// Problem: peak_map [256, 131072] f32, scalar logit_thresh.
// Outputs concatenated: smooth_peaks [256*131072] f32, peak_mask [256*131072] f32 (0/1).
#define ROWS 256
#define COLS 131072
#define SHARP 10.0f

// ext_vector type so __builtin_nontemporal_store accepts it (HIP float4 is a struct).
typedef float vf4 __attribute__((ext_vector_type(4)));

// Each thread handles 16 contiguous elements of one row (one full 64B cache line in,
// 2x64B out). Threads per row = COLS/16 = 8192 = 2^13.
// FP arithmetic is kept bitwise-identical to the previous passing kernel
// (expf + IEEE div) — only the memory schedule changes.
__global__ __launch_bounds__(256) void peak_extract_kernel(
    const float* __restrict__ x,
    const float* __restrict__ logit_thresh,
    float* __restrict__ smooth,
    float* __restrict__ mask)
{
    const float thresh = 1.0f / (1.0f + expf(-logit_thresh[0]));

    const long long gid = (long long)blockIdx.x * blockDim.x + threadIdx.x;
    const int row = (int)(gid >> 13);           // 2^13 threads per row
    const int col = ((int)gid & 8191) << 4;     // first element index within row

    const float* __restrict__ xr = x + (long long)row * COLS;

    // v[k] = xr[col-2+k], k = 0..19 (2-element halo each side, edge clamp).
    // 4 back-to-back dwordx4 loads -> 4 lines outstanding per thread.
    float v[20];
    const vf4 a0 = *(const vf4*)(xr + col);
    const vf4 a1 = *(const vf4*)(xr + col + 4);
    const vf4 a2 = *(const vf4*)(xr + col + 8);
    const vf4 a3 = *(const vf4*)(xr + col + 12);
    v[0]  = xr[max(col - 2, 0)];
    v[1]  = xr[max(col - 1, 0)];
    v[18] = xr[min(col + 16, COLS - 1)];
    v[19] = xr[min(col + 17, COLS - 1)];
#pragma unroll
    for (int k = 0; k < 4; ++k) {
        v[2 + k]  = a0[k];
        v[6 + k]  = a1[k];
        v[10 + k] = a2[k];
        v[14 + k] = a3[k];
    }

    const long long base = (long long)row * COLS + col;

#pragma unroll
    for (int q = 0; q < 4; ++q) {
        vf4 sv, mv;
#pragma unroll
        for (int k = 0; k < 4; ++k) {
            const int i = 4 * q + k;
            // pooled = max over window of 5 centered at element i (v[i..i+4])
            float p = v[i];
            p = fmaxf(p, v[i + 1]);
            p = fmaxf(p, v[i + 2]);
            p = fmaxf(p, v[i + 3]);
            p = fmaxf(p, v[i + 4]);
            const float xv   = v[i + 2];
            const float gate = 1.0f / (1.0f + expf(-SHARP * (xv - thresh)));
            const float lm   = 1.0f / (1.0f + expf(-SHARP * (xv - p)));
            const float s    = xv * gate * lm;
            sv[k] = s;
            mv[k] = (s >= thresh) ? 1.0f : 0.0f;
        }
        // Outputs are never re-read: non-temporal stores keep the 268 MB write
        // stream from evicting the input stream out of L2.
        __builtin_nontemporal_store(sv, (vf4*)(smooth + base + 4 * q));
        __builtin_nontemporal_store(mv, (vf4*)(mask + base + 4 * q));
    }
}

extern "C" void kernel_launch(void* const* d_in, const int* in_sizes, int n_in,
                              void* d_out, int out_size, void* d_ws, size_t ws_size,
                              hipStream_t stream) {
    const float* x            = (const float*)d_in[0];
    const float* logit_thresh = (const float*)d_in[1];

    float* smooth = (float*)d_out;                          // first output, ROWS*COLS f32
    float* mask   = (float*)d_out + (long long)ROWS * COLS; // second output, ROWS*COLS f32

    const long long n_elem   = (long long)ROWS * COLS;      // 33,554,432
    const long long n_thread = n_elem / 16;                 // 2,097,152
    const int block = 256;
    const int grid  = (int)(n_thread / block);              // 8,192

    peak_extract_kernel<<<grid, block, 0, stream>>>(x, logit_thresh, smooth, mask);
}

// Round 2
// 352.194 us; speedup vs baseline: 2.0088x; 2.0088x over previous
//
#include <hip/hip_runtime.h>
#include <math.h>

// Problem: peak_map [256, 131072] f32, scalar logit_thresh.
// Outputs concatenated: smooth_peaks [256*131072] f32, peak_mask [256*131072] f32 (0/1).
#define ROWS 256
#define COLS 131072
#define SHARP 10.0f

// ext_vector type so __builtin_nontemporal_store accepts it.
typedef float vf4 __attribute__((ext_vector_type(4)));

// Layout (round-1 lesson): each WAVE owns 1024 contiguous elements of one row.
// Lane l, chunk c (c=0..3) handles elements [wbase + c*256 + l*4, +4).
// => every load/store instruction is 64 lanes x 16B = 1KB CONTIGUOUS (full 64B
// lines), so non-temporal stores cannot cause partial-line write amplification
// (round 1: thread-contiguous layout + nt => 2.24x WRITE_SIZE blowup).
// Each thread still issues 4 independent vector-load streams for MLP.
// FP math kept bitwise identical to the round-0 passing kernel (expf + IEEE div)
// — mask flips at the s >= thresh boundary are the correctness cliff.
__global__ __launch_bounds__(256) void peak_extract_kernel(
    const float* __restrict__ x,
    const float* __restrict__ logit_thresh,
    float* __restrict__ smooth,
    float* __restrict__ mask)
{
    const float thresh = 1.0f / (1.0f + expf(-logit_thresh[0]));

    const long long gid = (long long)blockIdx.x * blockDim.x + threadIdx.x;
    const int wave = (int)(gid >> 6);
    const int lane = (int)(gid & 63);
    const long long wbase = (long long)wave << 10;   // 1024 elements per wave
    const int row  = (int)(wbase >> 17);             // COLS = 2^17
    const int col0 = (((int)wbase) & (COLS - 1)) + (lane << 2);

    const float* __restrict__ xr = x + (long long)row * COLS;

    // Issue all global loads up front: 4 independent 16B streams + scalar halos
    // (halos are L1/L2 hits — same lines the vector loads touch).
    vf4   a[4];
    float hl0[4], hl1[4], hr0[4], hr1[4];
#pragma unroll
    for (int c = 0; c < 4; ++c) {
        const int col = col0 + (c << 8);             // +256 elements per chunk
        a[c]   = *(const vf4*)(xr + col);
        hl0[c] = xr[max(col - 2, 0)];
        hl1[c] = xr[max(col - 1, 0)];
        hr0[c] = xr[min(col + 4, COLS - 1)];
        hr1[c] = xr[min(col + 5, COLS - 1)];
    }

    const long long rbase = (long long)row * COLS;

#pragma unroll
    for (int c = 0; c < 4; ++c) {
        const int col = col0 + (c << 8);
        float v[8];
        v[0] = hl0[c];
        v[1] = hl1[c];
        v[2] = a[c][0]; v[3] = a[c][1]; v[4] = a[c][2]; v[5] = a[c][3];
        v[6] = hr0[c];
        v[7] = hr1[c];

        vf4 sv, mv;
#pragma unroll
        for (int k = 0; k < 4; ++k) {
            // pooled = max over window of 5 centered at element k (v[k..k+4])
            float p = v[k];
            p = fmaxf(p, v[k + 1]);
            p = fmaxf(p, v[k + 2]);
            p = fmaxf(p, v[k + 3]);
            p = fmaxf(p, v[k + 4]);
            const float xv   = v[k + 2];
            const float gate = 1.0f / (1.0f + expf(-SHARP * (xv - thresh)));
            const float lm   = 1.0f / (1.0f + expf(-SHARP * (xv - p)));
            const float s    = xv * gate * lm;
            sv[k] = s;
            mv[k] = (s >= thresh) ? 1.0f : 0.0f;
        }
        __builtin_nontemporal_store(sv, (vf4*)(smooth + rbase + col));
        __builtin_nontemporal_store(mv, (vf4*)(mask   + rbase + col));
    }
}

extern "C" void kernel_launch(void* const* d_in, const int* in_sizes, int n_in,
                              void* d_out, int out_size, void* d_ws, size_t ws_size,
                              hipStream_t stream) {
    const float* x            = (const float*)d_in[0];
    const float* logit_thresh = (const float*)d_in[1];

    float* smooth = (float*)d_out;                          // first output, ROWS*COLS f32
    float* mask   = (float*)d_out + (long long)ROWS * COLS; // second output, ROWS*COLS f32

    const long long n_elem   = (long long)ROWS * COLS;      // 33,554,432
    const long long n_thread = n_elem / 16;                 // 2,097,152
    const int block = 256;
    const int grid  = (int)(n_thread / block);              // 8,192

    peak_extract_kernel<<<grid, block, 0, stream>>>(x, logit_thresh, smooth, mask);
}